// Round 9
// baseline (41.623 us; speedup 1.0000x reference)
//
#include <hip/hip_runtime.h>
#include <hip/hip_bf16.h>

#define NEGC (-1e8f)

__device__ __forceinline__ float lrelu(float x) { return x >= 0.f ? x : 0.2f * x; }

// Edge-logit computation. Used ONLY inside kA now; stats and alpha recompute
// it from the SAME LDS-resident s_self bits + same soj, so the -1e8
// amplification hazard is intra-block-consistent by construction (argmax
// entry gets exp(0)=1 exactly). No cross-kernel bit-identity needed anymore.
__device__ __forceinline__ void edge_pq(float ss, float soj, bool same,
                                        float& p, float& q) {
    float e = ss + soj;
    float pin = same ? e : e * NEGC;
    float nin = same ? e * NEGC : e;
    p = lrelu(pin);
    q = lrelu(nin);
}

// ---------------- Kernel A: 128 blocks x 512 thr; block b owns columns
// [8b, 8b+8). Computes u1/u2/c redundantly (e-order ROTATED per block — legal
// since bit-identity across blocks is no longer required), full s_self sweep
// (rotated stripes -> no lockstep L2 hotspot), per-column softmax stats, and
// materializes alpha rows: Arow[i][8b..8b+8] for all i. Everything stays in
// LDS; only Arow goes to global.
__global__ __launch_bounds__(512) void kA_alpha(
        const float* __restrict__ node, const int* __restrict__ group,
        const float* __restrict__ W_emb, const float* __restrict__ b_emb,
        const float* __restrict__ w_att, const float* __restrict__ b_att,
        float* __restrict__ Arow) {
    int t = threadIdx.x;
    int b = blockIdx.x;
    int wv = t >> 6, lane = t & 63;

    __shared__ float part[1024];
    __shared__ float u1[128], u2[128];
    __shared__ float sself[1024];
    __shared__ int   grp[1024];
    __shared__ float cc[2];
    __shared__ float soj_s[8], mp_s[8], ip_s[8], mn_s[8], iq_s[8];
    __shared__ int   gcol[8];

    grp[t] = group[t];
    grp[t + 512] = group[t + 512];

    // --- u1/u2 partials; e-order rotated by block id to spread W reads
    {
        int k = t & 127, q = t >> 7;
        float p1 = 0.f, p2 = 0.f;
        for (int ee = 0; ee < 32; ++ee) {
            int e = (32 * q + ee + b) & 127;
            float w = W_emb[e * 128 + k];
            p1 += w * w_att[e];
            p2 += w * w_att[128 + e];
        }
        part[q * 256 + k] = p1;
        part[q * 256 + 128 + k] = p2;
    }
    __syncthreads();
    if (t < 128) {
        u1[t] = part[t] + part[256 + t] + part[512 + t] + part[768 + t];
    } else if (t < 256) {
        int k = t - 128;
        u2[k] = part[128 + k] + part[384 + k] + part[640 + k] + part[896 + k];
    } else if (t < 320) {              // c1 = dot(b_emb, w_att[:128])
        int l = t - 256;
        float c = b_emb[l] * w_att[l] + b_emb[64 + l] * w_att[64 + l];
        for (int off = 32; off > 0; off >>= 1) c += __shfl_xor(c, off, 64);
        if (l == 0) cc[0] = c;
    } else if (t < 384) {              // c2 = dot(b_emb, w_att[128:])
        int l = t - 320;
        float c = b_emb[l] * w_att[128 + l] + b_emb[64 + l] * w_att[192 + l];
        for (int off = 32; off > 0; off >>= 1) c += __shfl_xor(c, off, 64);
        if (l == 0) cc[1] = c;
    }
    __syncthreads();

    // --- s_self for ALL rows: 16 groups x 32 lanes, stripes rotated by block
    {
        int g32 = t >> 5, l32 = t & 31;
        float4 uv = ((const float4*)u2)[l32];
        float c2 = cc[1];
        for (int it = 0; it < 64; ++it) {
            int row = (((it + b) & 63) << 4) + g32;
            float4 x = ((const float4*)(node + (size_t)row * 128))[l32];
            float d = x.x * uv.x + x.y * uv.y + x.z * uv.z + x.w * uv.w;
#pragma unroll
            for (int off = 16; off > 0; off >>= 1) d += __shfl_xor(d, off, 64);
            if (l32 == 0) sself[row] = d + c2;
        }
    }
    // --- soj for the block's 8 columns: wave wv -> col 8b+wv
    {
        int j = b * 8 + wv;
        const float2* row2 = (const float2*)(node + (size_t)j * 128);
        const float2* u12 = (const float2*)u1;
        float2 x = row2[lane], v = u12[lane];
        float d = x.x * v.x + x.y * v.y;
#pragma unroll
        for (int off = 32; off > 0; off >>= 1) d += __shfl_xor(d, off, 64);
        if (lane == 0) {
            soj_s[wv] = (d + cc[0]) + b_att[0];  // one fixed association,
            gcol[wv] = grp[j];                   // reused by stats AND alpha
        }
    }
    __syncthreads();

    // --- column stats: wave wv -> col 8b+wv (from LDS sself)
    {
        float soj = soj_s[wv];
        int gj = gcol[wv];
        float pv[16], nv[16];
        float pmax = -3.4e38f, nmax = -3.4e38f;
#pragma unroll
        for (int k = 0; k < 16; ++k) {
            int i = lane + k * 64;
            float p, q;
            edge_pq(sself[i], soj, grp[i] == gj, p, q);
            pv[k] = p; nv[k] = q;
            pmax = fmaxf(pmax, p);
            nmax = fmaxf(nmax, q);
        }
#pragma unroll
        for (int off = 32; off > 0; off >>= 1) {
            pmax = fmaxf(pmax, __shfl_xor(pmax, off, 64));
            nmax = fmaxf(nmax, __shfl_xor(nmax, off, 64));
        }
        float ps = 0.f, ns = 0.f;
#pragma unroll
        for (int k = 0; k < 16; ++k) {
            ps += __expf(pv[k] - pmax);
            ns += __expf(nv[k] - nmax);
        }
#pragma unroll
        for (int off = 32; off > 0; off >>= 1) {
            ps += __shfl_xor(ps, off, 64);
            ns += __shfl_xor(ns, off, 64);
        }
        if (lane == 0) {
            mp_s[wv] = pmax; ip_s[wv] = 1.f / ps;
            mn_s[wv] = nmax; iq_s[wv] = 1.f / ns;
        }
    }
    __syncthreads();

    // --- alpha: thread t -> rows i = t, t+512; 8 cols; 2x float4 store per i
    float sojr[8], mpr[8], ipr[8], mnr[8], iqr[8]; int gcr[8];
#pragma unroll
    for (int jj = 0; jj < 8; ++jj) {
        sojr[jj] = soj_s[jj]; mpr[jj] = mp_s[jj]; ipr[jj] = ip_s[jj];
        mnr[jj] = mn_s[jj]; iqr[jj] = iq_s[jj]; gcr[jj] = gcol[jj];
    }
#pragma unroll
    for (int e = 0; e < 2; ++e) {
        int i = t + e * 512;
        float ss = sself[i];
        int gi = grp[i];
        float a[8];
#pragma unroll
        for (int jj = 0; jj < 8; ++jj) {
            float p, q;
            edge_pq(ss, sojr[jj], gi == gcr[jj], p, q);  // same bits as stats
            a[jj] = __expf(p - mpr[jj]) * ipr[jj] + __expf(q - mnr[jj]) * iqr[jj];
        }
        float* dst = Arow + (size_t)i * 1024 + b * 8;
        *(float4*)dst       = make_float4(a[0], a[1], a[2], a[3]);
        *(float4*)(dst + 4) = make_float4(a[4], a[5], a[6], a[7]);
    }
}

// ---------------- Kernel B: out[i,:] = sum_j A[i,j] * relu(node[j,:])
// BI=4 rows/block, 256 blocks x 512 thr. A rows LOADED (coalesced, 16 KB)
// instead of recomputed; rotated node sweep spreads L2 requests; R4-proven
// reduce tail.
#define BI 4
__global__ __launch_bounds__(512) void kB_out(
        const float* __restrict__ node,
        const float* __restrict__ Arow,
        float* __restrict__ out) {
    int t = threadIdx.x;       // 0..511
    int bb = blockIdx.x;
    int i0 = bb * BI;

    __shared__ float buf[8192];   // 32 KB; first 4096 = sA[4][1024]
    {
        const float4* src = (const float4*)(Arow + (size_t)i0 * 1024);
        float4* dst = (float4*)buf;
        dst[t]       = src[t];
        dst[t + 512] = src[t + 512];
    }
    __syncthreads();

    int lane = t & 31;   // float4 index within a 128-d row
    int g = t >> 5;      // j-group 0..15
    const float4* nf4 = (const float4*)node;

    float4 acc[BI];
#pragma unroll
    for (int r = 0; r < BI; ++r) acc[r] = make_float4(0.f, 0.f, 0.f, 0.f);

    int boff = bb & 63;
#pragma unroll 8
    for (int jj = 0; jj < 64; ++jj) {
        int j = (((jj + boff) & 63) << 4) + g;    // rotated sweep
        float4 x = nf4[(size_t)j * 32 + lane];
        float4 rn;
        rn.x = fmaxf(x.x, 0.f); rn.y = fmaxf(x.y, 0.f);
        rn.z = fmaxf(x.z, 0.f); rn.w = fmaxf(x.w, 0.f);
#pragma unroll
        for (int r = 0; r < BI; ++r) {
            float a = buf[r * 1024 + j];
            acc[r].x += a * rn.x; acc[r].y += a * rn.y;
            acc[r].z += a * rn.z; acc[r].w += a * rn.w;
        }
    }

    __syncthreads();  // done reading sA; reuse buf as reduce buffer
    float4* red = (float4*)buf;   // red[g*128 + r*32 + lane], 2048 float4
#pragma unroll
    for (int r = 0; r < BI; ++r) red[g * 128 + r * 32 + lane] = acc[r];
    __syncthreads();

    // 512 outputs (BI rows x 128 d); 1 per thread, contiguous store
    int r = t >> 7;
    int d = t & 127;
    float sum = 0.f;
#pragma unroll
    for (int gg = 0; gg < 16; ++gg)
        sum += buf[gg * 512 + r * 128 + d];
    out[(size_t)(i0 + r) * 128 + d] = sum;
}

extern "C" void kernel_launch(void* const* d_in, const int* in_sizes, int n_in,
                              void* d_out, int out_size, void* d_ws, size_t ws_size,
                              hipStream_t stream) {
    const float* node  = (const float*)d_in[0];
    const int*   group = (const int*)d_in[1];
    const float* W_emb = (const float*)d_in[2];
    const float* b_emb = (const float*)d_in[3];
    const float* w_att = (const float*)d_in[4];
    const float* b_att = (const float*)d_in[5];
    float* out = (float*)d_out;

    float* Arow = (float*)d_ws;   // 1024 x 1024 f32 = 4 MB, fully rewritten

    kA_alpha<<<128, 512, 0, stream>>>(node, group, W_emb, b_emb, w_att, b_att,
                                      Arow);
    kB_out<<<256, 512, 0, stream>>>(node, Arow, out);
}

// Round 10
// 23.150 us; speedup vs baseline: 1.7979x; 1.7979x over previous
//
#include <hip/hip_runtime.h>
#include <hip/hip_bf16.h>

#define NEGC (-1e8f)

__device__ __forceinline__ float lrelu(float x) { return x >= 0.f ? x : 0.2f * x; }

// Edge-logit computation. MUST be bit-identical between the stats pass (k2)
// and the output pass (k3): the neg-mask multiplies e by -1e8, so a 1-ulp
// difference becomes ~±50 in the logit and exp() explodes. Add/mul only,
// fixed association e = ss + soj. k2 STORES the exact soj bits it used
// (sojd[j]); k3 reloads them -> cross-kernel consistency is store/reload.
__device__ __forceinline__ void edge_pq(float ss, float soj, bool same,
                                        float& p, float& q) {
    float e = ss + soj;
    float pin = same ? e : e * NEGC;
    float nin = same ? e * NEGC : e;
    p = lrelu(pin);
    q = lrelu(nin);
}

// ---------------- Kernel 1: scores. 8 blocks x 512 thr (4x the TLP of the R4
// version). u-phase quarter-split; score phase 4 threads/row.
__global__ __launch_bounds__(512) void k1_scores(
        const float* __restrict__ node,
        const float* __restrict__ W_emb,
        const float* __restrict__ b_emb,
        const float* __restrict__ w_att,
        float* __restrict__ s_other_g, float* __restrict__ s_self_g) {
    int t = threadIdx.x;
    int b = blockIdx.x;

    __shared__ float part[1024];
    __shared__ float u1[128], u2[128];
    __shared__ float cc[2];

    // u1/u2 partials: quarter q of the e-range, column k
    {
        int k = t & 127, q = t >> 7;
        float p1 = 0.f, p2 = 0.f;
        for (int e = 32 * q; e < 32 * q + 32; ++e) {
            float w = W_emb[e * 128 + k];
            p1 += w * w_att[e];
            p2 += w * w_att[128 + e];
        }
        part[q * 256 + k] = p1;
        part[q * 256 + 128 + k] = p2;
    }
    __syncthreads();
    if (t < 128) {
        u1[t] = part[t] + part[256 + t] + part[512 + t] + part[768 + t];
    } else if (t < 256) {
        int k = t - 128;
        u2[k] = part[128 + k] + part[384 + k] + part[640 + k] + part[896 + k];
    } else if (t < 320) {              // c1 = dot(b_emb, w_att[:128])
        int l = t - 256;
        float c = b_emb[l] * w_att[l] + b_emb[64 + l] * w_att[64 + l];
        for (int off = 32; off > 0; off >>= 1) c += __shfl_xor(c, off, 64);
        if (l == 0) cc[0] = c;
    } else if (t < 384) {              // c2 = dot(b_emb, w_att[128:])
        int l = t - 320;
        float c = b_emb[l] * w_att[128 + l] + b_emb[64 + l] * w_att[192 + l];
        for (int off = 32; off > 0; off >>= 1) c += __shfl_xor(c, off, 64);
        if (l == 0) cc[1] = c;
    }
    __syncthreads();

    // scores: row = b*128 + t/4; quarter q = t&3 covers 32 elems (8 float4)
    {
        int row = b * 128 + (t >> 2);
        int q = t & 3;
        const float4* row4 = (const float4*)(node + (size_t)row * 128);
        const float4* u14 = (const float4*)u1;
        const float4* u24 = (const float4*)u2;
        float d1 = 0.f, d2 = 0.f;
#pragma unroll
        for (int k = 0; k < 8; ++k) {
            float4 x = row4[q * 8 + k];
            float4 v1 = u14[q * 8 + k];
            float4 v2 = u24[q * 8 + k];
            d1 += x.x * v1.x + x.y * v1.y + x.z * v1.z + x.w * v1.w;
            d2 += x.x * v2.x + x.y * v2.y + x.z * v2.z + x.w * v2.w;
        }
        d1 += __shfl_xor(d1, 1, 64); d1 += __shfl_xor(d1, 2, 64);
        d2 += __shfl_xor(d2, 1, 64); d2 += __shfl_xor(d2, 2, 64);
        if (q == 0) {
            s_other_g[row] = d1 + cc[0];
            s_self_g[row]  = d2 + cc[1];
        }
    }
}

// ---------------- Kernel 2: per-column softmax stats (R4-proven). One wave
// per column, 4 columns/block. Stores sojd[j] (exact soj bits used) and
// packed stats4[j] = (pmax, 1/psum, nmax, 1/nsum).
__global__ __launch_bounds__(256) void k2_col_stats(
        const float* __restrict__ s_self,
        const float* __restrict__ s_other,
        const int* __restrict__ group,
        const float* __restrict__ b_att,
        float* __restrict__ sojd, float4* __restrict__ stats4) {
    int j = blockIdx.x * 4 + (threadIdx.x >> 6);
    int lane = threadIdx.x & 63;
    float soj = s_other[j] + b_att[0];   // the one fixed association
    int gj = group[j];

    float pv[16], nv[16];
    float pmax = -3.4e38f, nmax = -3.4e38f;
#pragma unroll
    for (int k = 0; k < 16; ++k) {
        int i = lane + k * 64;
        float p, q;
        edge_pq(s_self[i], soj, group[i] == gj, p, q);
        pv[k] = p; nv[k] = q;
        pmax = fmaxf(pmax, p);
        nmax = fmaxf(nmax, q);
    }
#pragma unroll
    for (int off = 32; off > 0; off >>= 1) {
        pmax = fmaxf(pmax, __shfl_xor(pmax, off, 64));
        nmax = fmaxf(nmax, __shfl_xor(nmax, off, 64));
    }
    float ps = 0.f, ns = 0.f;
#pragma unroll
    for (int k = 0; k < 16; ++k) {
        ps += __expf(pv[k] - pmax);
        ns += __expf(nv[k] - nmax);
    }
#pragma unroll
    for (int off = 32; off > 0; off >>= 1) {
        ps += __shfl_xor(ps, off, 64);
        ns += __shfl_xor(ns, off, 64);
    }
    if (lane == 0) {
        sojd[j] = soj;
        stats4[j] = make_float4(pmax, 1.f / ps, nmax, 1.f / ns);
    }
}

// ---------------- Kernel 3: out[i,:] = sum_j A[i,j] * relu(node[j,:])
// BI=4 rows/block, 256 blocks x 512 thr (R4-proven shape). A packed as
// float4 bufA[j] = alpha for the block's 4 rows -> single b128 broadcast
// read per j in the main loop. Reduce tail verbatim from R4.
#define BI 4
__global__ __launch_bounds__(512) void k3_out(
        const float* __restrict__ node,
        const float* __restrict__ s_self,
        const int* __restrict__ group,
        const float* __restrict__ sojd,
        const float4* __restrict__ stats4,
        float* __restrict__ out) {
    int t = threadIdx.x;       // 0..511
    int i0 = blockIdx.x * BI;

    __shared__ float buf[8192];   // 32 KB: first 1024 float4 = bufA, then reduce
    __shared__ float ss_l[BI];
    __shared__ int   g_l[BI];
    if (t < BI) { ss_l[t] = s_self[i0 + t]; g_l[t] = group[i0 + t]; }
    __syncthreads();

    float ssr[BI]; int glr[BI];
#pragma unroll
    for (int r = 0; r < BI; ++r) { ssr[r] = ss_l[r]; glr[r] = g_l[r]; }

    float4* bufA = (float4*)buf;
#pragma unroll
    for (int e = 0; e < 2; ++e) {
        int j = t + e * 512;
        float soj = sojd[j];            // exact bits k2 used
        float4 st = stats4[j];
        int gj = group[j];
        float a[BI];
#pragma unroll
        for (int r = 0; r < BI; ++r) {
            float p, q;
            edge_pq(ssr[r], soj, gj == glr[r], p, q);
            a[r] = __expf(p - st.x) * st.y + __expf(q - st.z) * st.w;
        }
        bufA[j] = make_float4(a[0], a[1], a[2], a[3]);
    }
    __syncthreads();

    int lane = t & 31;   // float4 index within a 128-d row
    int g = t >> 5;      // j-group 0..15
    const float4* nf4 = (const float4*)node;

    float4 acc[BI];
#pragma unroll
    for (int r = 0; r < BI; ++r) acc[r] = make_float4(0.f, 0.f, 0.f, 0.f);

#pragma unroll 8
    for (int j = g; j < 1024; j += 16) {
        float4 x = nf4[(size_t)j * 32 + lane];
        float4 rn;
        rn.x = fmaxf(x.x, 0.f); rn.y = fmaxf(x.y, 0.f);
        rn.z = fmaxf(x.z, 0.f); rn.w = fmaxf(x.w, 0.f);
        float4 a4 = bufA[j];            // broadcast b128
        acc[0].x += a4.x * rn.x; acc[0].y += a4.x * rn.y;
        acc[0].z += a4.x * rn.z; acc[0].w += a4.x * rn.w;
        acc[1].x += a4.y * rn.x; acc[1].y += a4.y * rn.y;
        acc[1].z += a4.y * rn.z; acc[1].w += a4.y * rn.w;
        acc[2].x += a4.z * rn.x; acc[2].y += a4.z * rn.y;
        acc[2].z += a4.z * rn.z; acc[2].w += a4.z * rn.w;
        acc[3].x += a4.w * rn.x; acc[3].y += a4.w * rn.y;
        acc[3].z += a4.w * rn.z; acc[3].w += a4.w * rn.w;
    }

    __syncthreads();  // done reading bufA; reuse buf as reduce buffer
    float4* red = (float4*)buf;   // red[g*128 + r*32 + lane], 2048 float4
#pragma unroll
    for (int r = 0; r < BI; ++r) red[g * 128 + r * 32 + lane] = acc[r];
    __syncthreads();

    // 512 outputs (BI rows x 128 d); 1 per thread, contiguous store
    int r = t >> 7;
    int d = t & 127;
    float sum = 0.f;
#pragma unroll
    for (int gg = 0; gg < 16; ++gg)
        sum += buf[gg * 512 + r * 128 + d];
    out[(size_t)(i0 + r) * 128 + d] = sum;
}

extern "C" void kernel_launch(void* const* d_in, const int* in_sizes, int n_in,
                              void* d_out, int out_size, void* d_ws, size_t ws_size,
                              hipStream_t stream) {
    const float* node  = (const float*)d_in[0];
    const int*   group = (const int*)d_in[1];
    const float* W_emb = (const float*)d_in[2];
    const float* b_emb = (const float*)d_in[3];
    const float* w_att = (const float*)d_in[4];
    const float* b_att = (const float*)d_in[5];
    float* out = (float*)d_out;

    float* w = (float*)d_ws;
    float*  s_other = w;               // 1024
    float*  s_self  = w + 1024;        // 1024
    float*  sojd    = w + 2048;        // 1024
    float4* stats4  = (float4*)(w + 3072);  // 1024 float4 (16B-aligned)

    k1_scores<<<8, 512, 0, stream>>>(node, W_emb, b_emb, w_att,
                                     s_other, s_self);
    k2_col_stats<<<256, 256, 0, stream>>>(s_self, s_other, group, b_att,
                                          sojd, stats4);
    k3_out<<<256, 512, 0, stream>>>(node, s_self, group, sojd, stats4, out);
}